// Round 3
// baseline (452.568 us; speedup 1.0000x reference)
//
#include <hip/hip_runtime.h>
#include <math.h>

#define Bn 256
#define Cc 3
#define Hh 256
#define Ww 256
#define HW (Hh*Ww)        // 65536
#define CHW (Cc*HW)       // 196608

// ws layout (floats): [0..255] per-image sums, then per-image params stride 10
#define P_BASE 256
#define P_STRIDE 10
// param indices: 0 cth, 1 sth, 2 flip, 3 startY, 4 scaleY, 5 startX, 6 scaleX,
//                7 delta, 8 mag1, 9 mag2

#define TS 16             // output tile
#define RY 29             // L1 staged rows (rotated bbox of 18x18 patch)
#define RXS 33            // L1 col stride: 32 loaded cols + 1 pad (odd stride ->
                          // bank = (row+col)%32; per-image mirror keeps the lane
                          // walk's bank step >= 1 always)
#define PLANE1 (RY*RXS)           // 957
#define N1 (Cc*PLANE1)            // 2871 floats = 11484 B
#define S2 18             // stage-2 patch dim (17 + 1 fp-edge guard row/col)
#define S2S 20            // stage-2 LDS row stride
#define PLANE2 (S2*S2S)           // 360

typedef float f4v __attribute__((ext_vector_type(4)));

__global__ void setup_params(const float* __restrict__ th, const float* __restrict__ fl,
                             const float* __restrict__ sz, const float* __restrict__ sh,
                             const float* __restrict__ de, const float* __restrict__ m1,
                             const float* __restrict__ m2, float* __restrict__ ws) {
    int b = threadIdx.x;   // one thread per image
    ws[b] = 0.0f;          // zero the sum slot (ws poisoned 0xAA each launch)
    float* p = ws + P_BASE + b * P_STRIDE;
    float theta = (th[b] * 2.0f - 1.0f) * 3.14159265358979323846f;  // ROT_DEG=180 -> pi
    p[0] = cosf(theta);
    p[1] = sinf(theta);
    p[2] = (fl[b] > 0.5f) ? 1.0f : 0.0f;
    #pragma unroll
    for (int d = 0; d < 2; d++) {   // d=0 -> y (rows), d=1 -> x (cols)
        float s     = rintf(256.0f * (sz[b*2 + d] * 0.25f + 1.0f) - 0.5f); // jnp.round = rint
        float ms    = s - 256.0f;
        float sr    = ms - 1e-5f;
        float shf   = rintf(sh[b*2 + d] * sr - sr * 0.5f);
        float start = floorf(ms * 0.5f) + shf;
        p[3 + 2*d]  = start;
        p[4 + 2*d]  = 255.0f / (s - 1.0f);
    }
    p[7] = (de[b] * 2.0f - 1.0f) * 0.3f;
    p[8] = (m1[b] * 2.0f - 1.0f) * 0.3f + 1.0f;
    p[9] = (m2[b] * 2.0f - 1.0f) * 0.3f + 1.0f;
}

// Per-tile prologue, hoisted out of augment_main (block-uniform float math has
// no scalar-FP home on CDNA -> every wave paid ~75 VALU for it). One thread per
// tile; results stored in the tile's OWN channel-0 row-0 pixels of `out`
// (only that tile's block reads them, and only it overwrites them in Phase C).
__global__ __launch_bounds__(256)
void tile_params(const float* __restrict__ wsp, float* __restrict__ out) {
    const int b = blockIdx.x;
    const int t = threadIdx.x;
    const int tileY = t & 0xF0;          // (t>>4)*16
    const int tileX = (t & 15) << 4;
    const float* p = wsp + P_BASE + b * P_STRIDE;
    const float cth = p[0], sth = p[1];
    const bool  flip = p[2] > 0.5f;
    const float startY = p[3], scaleY = p[4];
    const float startX = p[5], scaleX = p[6];
    const bool  mir = (cth * sth) < 0.0f;

    float sy0 = fminf(fmaxf((startY + (float)tileY) * scaleY, 0.0f), 255.0f);
    float sx0 = fminf(fmaxf((startX + (float)tileX) * scaleX, 0.0f), 255.0f);
    const int rYi = (int)floorf(sy0);
    const int rXi = (int)floorf(sx0);

    const int Ymax = min(rYi + S2 - 1, 255);
    const int Xt1  = min(rXi + S2 - 1, 255);
    const int Xf0  = flip ? 255 - Xt1 : rXi;
    const int Xf1  = flip ? 255 - rXi : Xt1;
    const float xg0 = fmaf((float)Xf0, 0.0078125f, -0.99609375f);
    const float xg1 = fmaf((float)Xf1, 0.0078125f, -0.99609375f);
    const float yg0 = fmaf((float)rYi, 0.0078125f, -0.99609375f);
    const float yg1 = fmaf((float)Ymax,0.0078125f, -0.99609375f);

    float ixmin = 1e30f, iymin = 1e30f, ixmax = -1e30f, iymax = -1e30f;
    #pragma unroll
    for (int cy = 0; cy < 2; cy++) {
        #pragma unroll
        for (int cx = 0; cx < 2; cx++) {
            float xg = cx ? xg1 : xg0;
            float yg = cy ? yg1 : yg0;
            float xp = cth * xg - sth * yg;
            float yp = sth * xg + cth * yg;
            float tx = fmaf(xp, 128.0f, 127.5f);
            float ty = fmaf(yp, 128.0f, 127.5f);
            ixmin = fminf(ixmin, tx); ixmax = fmaxf(ixmax, tx);
            iymin = fminf(iymin, ty); iymax = fmaxf(iymax, ty);
        }
    }
    const int bx0  = (int)floorf(ixmin) - 1;
    const int by0  = (int)floorf(iymin) - 1;
    const int bx0a = bx0 & ~3;
    // +1 guard row/col vs the minimal bound: affine re-rounding can push a
    // site's floor() one past the corner-derived bbox.
    const int rneed = min(RY, (int)floorf(iymax) - by0 + 3);
    const int cneed = min(32, (int)floorf(ixmax) - bx0a + 3);
    const bool interior = (ixmin >= 0.0f) && (iymin >= 0.0f) &&
                          (ixmax < 255.0f) && (iymax < 255.0f);
    const bool affineOK = (rYi <= 255 - (S2 - 1)) && (rXi <= 255 - (S2 - 1));
    const bool fastA    = (bx0a >= 0) && (bx0a <= 224);
    const int flags = (mir ? 1 : 0) | ((interior && affineOK) ? 2 : 0)
                    | (fastA ? 4 : 0);

    // affine base coords at (lY=0, lX=0) -- valid when affineOK (no clamps)
    const int Xfs = flip ? 255 - rXi : rXi;
    float xg = fmaf((float)Xfs, 0.0078125f, -0.99609375f);
    float yg = fmaf((float)rYi, 0.0078125f, -0.99609375f);
    float xp = cth * xg - sth * yg;
    float yp = sth * xg + cth * yg;
    float ix00 = fmaf(xp, 128.0f, 127.5f);
    float iy00 = fmaf(yp, 128.0f, 127.5f);

    float* tp = out + (size_t)b * CHW + (tileY << 8) + tileX;
    tp[0] = (float)bx0a;  tp[1] = (float)by0;
    tp[2] = (float)rYi;   tp[3] = (float)rXi;
    tp[4] = (float)flags; tp[5] = ix00; tp[6] = iy00;
    tp[7] = (float)rneed; tp[8] = (float)cneed;
}

// General Phase-B body (edge tiles): clamps + zeros-pad validity, i/18 decompose.
#define PHASE_B_GENERAL(MIR)                                                  \
    for (int i = tid; i < S2 * S2; i += 256) {                                \
        int lY = i / S2;                                                      \
        int lX = i - lY * S2;                                                 \
        int Yc = min(rY + lY, 255);                                           \
        int Xc = min(rX + lX, 255);                                           \
        int Xf = flip ? 255 - Xc : Xc;                                        \
        float xg = fmaf((float)Xf, 0.0078125f, -0.99609375f);                 \
        float yg = fmaf((float)Yc, 0.0078125f, -0.99609375f);                 \
        float xp = cth * xg - sth * yg;                                       \
        float yp = sth * xg + cth * yg;                                       \
        float ixf = fmaf(xp, 128.0f, 127.5f);                                 \
        float iyf = fmaf(yp, 128.0f, 127.5f);                                 \
        float x0f = floorf(ixf), y0f = floorf(iyf);                           \
        float fx = ixf - x0f, fy = iyf - y0f;                                 \
        float wx0 = (x0f >=  0.0f && x0f <= 255.0f) ? (1.0f - fx) : 0.0f;     \
        float wx1 = (x0f >= -1.0f && x0f <= 254.0f) ? fx          : 0.0f;     \
        float wy0 = (y0f >=  0.0f && y0f <= 255.0f) ? (1.0f - fy) : 0.0f;     \
        float wy1 = (y0f >= -1.0f && y0f <= 254.0f) ? fy          : 0.0f;     \
        int ax = (int)x0f - bx0a;                                             \
        int ay = (int)y0f - by0;                                              \
        int base = ay * RXS + (MIR ? (30 - ax) : ax);                         \
        float A0 = MIR ? wx1 : wx0;   /* x-weight for L[base] */              \
        float A1 = MIR ? wx0 : wx1;                                           \
        float w00 = wy0 * A0, w01 = wy0 * A1;                                 \
        float w10 = wy1 * A0, w11 = wy1 * A1;                                 \
        int ob = lY * S2S + lX;                                               \
        _Pragma("unroll")                                                     \
        for (int c = 0; c < Cc; c++) {                                        \
            const float* Lc = L1 + c * PLANE1;                                \
            float v = w00 * Lc[base]       + w01 * Lc[base + 1]               \
                    + w10 * Lc[base + RXS] + w11 * Lc[base + RXS + 1];        \
            L2[c * PLANE2 + ob] = v;                                          \
        }                                                                     \
    }

// Affine Phase-B site: coords are affine in (lX,lY); no clamps, no validity.
#define B_SITE_AFFINE(MIR, LYv, LXv)                                          \
    {                                                                         \
        float lXf = (float)(LXv), lYf = (float)(LYv);                         \
        float ixf = fmaf(lYf, DxY, fmaf(lXf, DxX, ix00));                     \
        float iyf = fmaf(lYf, DyY, fmaf(lXf, DyX, iy00));                     \
        float x0f = floorf(ixf), y0f = floorf(iyf);                           \
        float fx = ixf - x0f, fy = iyf - y0f;                                 \
        int ax = (int)x0f - bx0a;                                             \
        int ay = (int)y0f - by0;                                              \
        int base = ay * RXS + (MIR ? (30 - ax) : ax);                         \
        float A0 = MIR ? fx : (1.0f - fx);                                    \
        float A1 = MIR ? (1.0f - fx) : fx;                                    \
        float wy0 = 1.0f - fy;                                                \
        float w00 = wy0 * A0, w01 = wy0 * A1;                                 \
        float w10 = fy * A0,  w11 = fy * A1;                                  \
        int ob = (LYv) * S2S + (LXv);                                         \
        _Pragma("unroll")                                                     \
        for (int c = 0; c < Cc; c++) {                                        \
            const float* Lc = L1 + c * PLANE1;                                \
            float v = w00 * Lc[base]       + w01 * Lc[base + 1]               \
                    + w10 * Lc[base + RXS] + w11 * Lc[base + RXS + 1];        \
            L2[c * PLANE2 + ob] = v;                                          \
        }                                                                     \
    }

// 16x16 main grid (shr/and mapping, no division) + 68-site L-border pass.
#define PHASE_B_AFFINE(MIR)                                                   \
    {                                                                         \
        { int lY = tid >> 4, lX = tid & 15; B_SITE_AFFINE(MIR, lY, lX) }      \
        if (tid < 68) {                                                       \
            bool top = tid < 36;                                              \
            int j = tid - 36;                                                 \
            int lY = top ? (16 + (tid >= 18 ? 1 : 0)) : (j >> 1);             \
            int lX = top ? (tid - (tid >= 18 ? 18 : 0)) : (16 + (j & 1));     \
            B_SITE_AFFINE(MIR, lY, lX)                                        \
        }                                                                     \
    }

__global__ __launch_bounds__(256)
void augment_main(const float* __restrict__ img, const float* __restrict__ wsp,
                  float* out, float* __restrict__ sums) {
    __shared__ float L1[N1];        // rotated-source staging (11484 B)
    __shared__ float L2[Cc*PLANE2]; // stage-2 patch 18x18, stride 20 (4320 B)
    __shared__ float wred[4];

    const int tid = threadIdx.x;

    // XCD-contiguous swizzle (bijective: 65536 % 8 == 0).
    const int lin = blockIdx.x + (blockIdx.y << 4) + (blockIdx.z << 8);
    const int nid = (lin & 7) * (65536 / 8) + (lin >> 3);
    const int b     = nid >> 8;
    const int tileY = ((nid >> 4) & 15) << 4;
    const int tileX = (nid & 15) << 4;

    const float* p = wsp + P_BASE + b * P_STRIDE;
    const float cth = p[0], sth = p[1];
    const bool  flip = p[2] > 0.5f;
    const float startY = p[3], scaleY = p[4];
    const float startX = p[5], scaleX = p[6];
    const float delta = p[7], mag1 = p[8];

    // precomputed per-tile params (uniform address -> scalar loads)
    const float* tp = out + (size_t)b * CHW + (tileY << 8) + tileX;
    const int   bx0a = (int)tp[0], by0 = (int)tp[1];
    const int   rY   = (int)tp[2], rX  = (int)tp[3];
    const int   flags = (int)tp[4];
    const float ix00 = tp[5], iy00 = tp[6];
    const int   rneed = (int)tp[7], cneed = (int)tp[8];
    const bool mir   = (flags & 1) != 0;
    const bool v0    = (flags & 2) != 0;
    const bool fastA = (flags & 4) != 0;

    // affine coordinate slopes (per-image): d(ixf)/dlX etc.
    const float DxX = flip ? -cth : cth;
    const float DyX = flip ? -sth : sth;
    const float DxY = -sth;
    const float DyY = cth;

    // ---- Phase A: load rneed rows x cneed cols x 3 ch into LDS ----
    const float* imgb = img + (size_t)b * CHW;
    {
        const int r  = tid >> 3;
        const int c4 = (tid & 7) << 2;
        if (r < rneed && c4 < cneed) {
            const int ry = min(max(by0 + r, 0), 255);
            const float* srow = imgb + (ry << 8);
            if (fastA) {
                const float* s0 = srow + bx0a + c4;
                if (!mir) {
                    float* d = L1 + r * RXS + c4;
                    #pragma unroll
                    for (int ch = 0; ch < Cc; ch++) {
                        float4 v = *(const float4*)(s0 + (ch << 16));
                        float* dd = d + ch * PLANE1;
                        dd[0] = v.x; dd[1] = v.y; dd[2] = v.z; dd[3] = v.w;
                    }
                } else {
                    float* d = L1 + r * RXS + (28 - c4);  // sx = 31-(c4+j)
                    #pragma unroll
                    for (int ch = 0; ch < Cc; ch++) {
                        float4 v = *(const float4*)(s0 + (ch << 16));
                        float* dd = d + ch * PLANE1;
                        dd[0] = v.w; dd[1] = v.z; dd[2] = v.y; dd[3] = v.x;
                    }
                }
            } else {
                #pragma unroll
                for (int j = 0; j < 4; j++) {
                    int gx = min(max(bx0a + c4 + j, 0), 255);
                    int sx = mir ? (31 - (c4 + j)) : (c4 + j);
                    #pragma unroll
                    for (int ch = 0; ch < Cc; ch++)
                        L1[ch * PLANE1 + r * RXS + sx] = srow[(ch << 16) + gx];
                }
            }
        }
    }
    __syncthreads();

    // ---- Phase B: rotate (+flip remap) -> 18x18 stage-2 patch in LDS ----
    if (v0) {
        if (mir) { PHASE_B_AFFINE(true) } else { PHASE_B_AFFINE(false) }
    } else {
        if (mir) { PHASE_B_GENERAL(true) } else { PHASE_B_GENERAL(false) }
    }
    __syncthreads();

    // ---- Phase C: crop-resize bilinear (clamp mode) + color ops + sum ----
    const int py = tid >> 4, px = tid & 15;
    const int y = tileY + py, x = tileX + px;
    float sy = fminf(fmaxf((startY + (float)y) * scaleY, 0.0f), 255.0f);
    float sx = fminf(fmaxf((startX + (float)x) * scaleX, 0.0f), 255.0f);
    float y0f = floorf(sy), x0f = floorf(sx);
    float fy = sy - y0f, fx = sx - x0f;
    int ly = (int)y0f - rY;    // in [0,16]; +1 row exists (S2=18, clamp-replicated)
    int lx = (int)x0f - rX;
    int ib2 = ly * S2S + lx;
    float w00 = (1.0f - fy) * (1.0f - fx), w01 = (1.0f - fy) * fx;
    float w10 = fy * (1.0f - fx),          w11 = fy * fx;

    float vv[3];
    #pragma unroll
    for (int c = 0; c < Cc; c++) {
        const float* Lc = L2 + c * PLANE2;
        vv[c] = w00 * Lc[ib2]       + w01 * Lc[ib2 + 1]
              + w10 * Lc[ib2 + S2S] + w11 * Lc[ib2 + S2S + 1];
    }
    // v5 = ((v+delta) - mean(v+delta))*mag1 + mean(v+delta)
    //    = fma(v, mag1, mc*(1-mag1) + delta)
    float mc  = (vv[0] + vv[1] + vv[2]) * (1.0f/3.0f);
    float mck = fmaf(-mag1, mc, mc) + delta;
    float s5 = 0.0f;
    float* outb = out + (size_t)b * CHW + (y << 8) + x;
    #pragma unroll
    for (int c = 0; c < Cc; c++) {
        float v5 = fmaf(vv[c], mag1, mck);
        outb[c * HW] = v5;
        s5 += v5;
    }
    // block reduction of sum(x5)
    #pragma unroll
    for (int off = 32; off > 0; off >>= 1) s5 += __shfl_down(s5, off, 64);
    int lane = tid & 63, wid = tid >> 6;
    if (lane == 0) wred[wid] = s5;
    __syncthreads();
    if (tid == 0) atomicAdd(&sums[b], wred[0] + wred[1] + wred[2] + wred[3]);
}

__global__ __launch_bounds__(256)
void finalize_k(float* __restrict__ out, const float* __restrict__ wsp) {
    const int b = blockIdx.y;
    const float m    = wsp[b] * (1.0f / (float)CHW);
    const float mag2 = wsp[P_BASE + b * P_STRIDE + 9];
    f4v* ob = (f4v*)(out + (size_t)b * CHW);
    const int i0 = blockIdx.x * 256 + threadIdx.x;   // gridDim.x = 16 -> 4096 lanes/image
    #pragma unroll
    for (int k = 0; k < 12; k++) {
        int idx = i0 + k * 4096;                     // 12*4096 = 49152 = CHW/4
        f4v v = __builtin_nontemporal_load(&ob[idx]);
        v.x = fmaf(v.x - m, mag2, m);
        v.y = fmaf(v.y - m, mag2, m);
        v.z = fmaf(v.z - m, mag2, m);
        v.w = fmaf(v.w - m, mag2, m);
        __builtin_nontemporal_store(v, &ob[idx]);
    }
}

extern "C" void kernel_launch(void* const* d_in, const int* in_sizes, int n_in,
                              void* d_out, int out_size, void* d_ws, size_t ws_size,
                              hipStream_t stream) {
    const float* img = (const float*)d_in[0];
    const float* th  = (const float*)d_in[1];
    const float* fl  = (const float*)d_in[2];
    const float* sz  = (const float*)d_in[3];
    const float* sh  = (const float*)d_in[4];
    const float* de  = (const float*)d_in[5];
    const float* m1  = (const float*)d_in[6];
    const float* m2  = (const float*)d_in[7];
    float* out = (float*)d_out;
    float* ws  = (float*)d_ws;

    hipLaunchKernelGGL(setup_params, dim3(1), dim3(256), 0, stream,
                       th, fl, sz, sh, de, m1, m2, ws);
    hipLaunchKernelGGL(tile_params, dim3(Bn), dim3(256), 0, stream,
                       ws, out);
    hipLaunchKernelGGL(augment_main, dim3(Ww/TS, Hh/TS, Bn), dim3(256), 0, stream,
                       img, ws, out, ws);
    hipLaunchKernelGGL(finalize_k, dim3(16, Bn), dim3(256), 0, stream,
                       out, ws);
}